// Round 5
// baseline (1223.254 us; speedup 1.0000x reference)
//
#include <hip/hip_runtime.h>
#include <hip/hip_bf16.h>

#define Bn   32
#define HWn  676
#define Cn   768
#define Mn   32
#define NC   200
#define KT   (Mn*Cn)      // 24576

#define LOGITS_OFF 0
#define ATTN_OFF   (Bn*NC)                 // 6400
#define EMB_OFF    (ATTN_OFF + Bn*HWn*Mn)  // 698624

// a_kernel: 16 position-tiles of 43, K=768 in 12 chunks of 64
#define PTA  43
#define NTA  16
#define KCA  64
#define NKA  (Cn/KCA)     // 12
#define XPA  66           // f7 tile row stride (floats): 264B, 8B-aligned, banks 2pq+k

// b_kernel: 16 channel-tiles of 48, K=676 in 11 chunks of 64
#define CTB  48
#define PCB  64
#define NPB  11

// ---------------- z: zero logits + norm accum --------------------------------
__global__ __launch_bounds__(256) void z_kernel(float* __restrict__ out,
                                                float* __restrict__ norm_acc) {
    int gid = blockIdx.x * 256 + threadIdx.x;
    int stride = gridDim.x * 256;
    for (int i = gid; i < Bn * NC; i += stride) out[LOGITS_OFF + i] = 0.f;
    for (int i = gid; i < Bn; i += stride) norm_acc[i] = 0.f;
}

// ---------------- a: attention GEMM, full-K, double-buffered LDS -------------
// grid = 32*16 = 512 blocks, 384 threads = (pq in 48[<43 active], mg in 8).
__global__ __launch_bounds__(384, 3) void a_kernel(const float* __restrict__ f7,
                                                   const float* __restrict__ wA,
                                                   float* __restrict__ attn) {
    __shared__ float xs[2][PTA * XPA];   // 2 x 11352 B
    __shared__ float wsh[2][KCA * Mn];   // 2 x 8192 B
    const int tid = threadIdx.x;
    const int b  = blockIdx.x >> 4;
    const int pt = blockIdx.x & 15;
    const int p0 = pt * PTA;
    const int mg = tid / 48;             // 0..7 -> m quad mg*4
    const int pq = tid - mg * 48;        // 0..47 (43..47 inactive)
    const int pqe = (pq < PTA) ? pq : (PTA - 1);

    const float* f7b = f7 + (size_t)b * HWn * Cn;

    float4 xr0, xr1, wr0, wr1;

#define ALOAD(kc) do {                                                          \
    int cbase = (kc) * KCA;                                                     \
    int r0 = tid >> 4, c40 = tid & 15;                                          \
    int gr0 = p0 + r0; if (gr0 > HWn - 1) gr0 = HWn - 1;                        \
    xr0 = *reinterpret_cast<const float4*>(f7b + (size_t)gr0 * Cn + cbase + c40 * 4); \
    int f1 = tid + 384;                                                         \
    if (f1 < PTA * 16) {                                                        \
        int r1 = f1 >> 4, c41 = f1 & 15;                                        \
        int gr1 = p0 + r1; if (gr1 > HWn - 1) gr1 = HWn - 1;                    \
        xr1 = *reinterpret_cast<const float4*>(f7b + (size_t)gr1 * Cn + cbase + c41 * 4); \
    }                                                                           \
    wr0 = *reinterpret_cast<const float4*>(wA + (size_t)cbase * Mn + tid * 4);  \
    if (tid < 128)                                                              \
        wr1 = *reinterpret_cast<const float4*>(wA + (size_t)cbase * Mn + (384 + tid) * 4); \
} while (0)

#define AWRITE(bw) do {                                                         \
    int r0 = tid >> 4, c40 = tid & 15;                                          \
    float* d0 = &xs[bw][r0 * XPA + c40 * 4];                                    \
    *reinterpret_cast<float2*>(d0)     = make_float2(xr0.x, xr0.y);             \
    *reinterpret_cast<float2*>(d0 + 2) = make_float2(xr0.z, xr0.w);             \
    int f1 = tid + 384;                                                         \
    if (f1 < PTA * 16) {                                                        \
        int r1 = f1 >> 4, c41 = f1 & 15;                                        \
        float* d1 = &xs[bw][r1 * XPA + c41 * 4];                                \
        *reinterpret_cast<float2*>(d1)     = make_float2(xr1.x, xr1.y);         \
        *reinterpret_cast<float2*>(d1 + 2) = make_float2(xr1.z, xr1.w);         \
    }                                                                           \
    *reinterpret_cast<float4*>(&wsh[bw][tid * 4]) = wr0;                        \
    if (tid < 128)                                                              \
        *reinterpret_cast<float4*>(&wsh[bw][(384 + tid) * 4]) = wr1;            \
} while (0)

    float4 acc = {0.f, 0.f, 0.f, 0.f};
    ALOAD(0);
    AWRITE(0);
    int buf = 0;
    for (int kc = 0; kc < NKA; ++kc) {
        __syncthreads();
        if (kc + 1 < NKA) ALOAD(kc + 1);      // global->reg, hidden under compute
        const float* xrow = &xs[buf][pqe * XPA];
        const float* wb   = &wsh[buf][mg * 4];
        #pragma unroll
        for (int k = 0; k < KCA; ++k) {
            float x = xrow[k];
            float4 w = *reinterpret_cast<const float4*>(wb + k * Mn);
            acc.x += x * w.x; acc.y += x * w.y; acc.z += x * w.z; acc.w += x * w.w;
        }
        if (kc + 1 < NKA) AWRITE(buf ^ 1);    // reg->LDS after compute
        buf ^= 1;
    }
    int p = p0 + pq;
    if (pq < PTA && p < HWn)
        *reinterpret_cast<float4*>(attn + ((size_t)b * HWn + p) * Mn + mg * 4) = acc;
#undef ALOAD
#undef AWRITE
}

// ---------------- b: pooling GEMM, full-K, fused ssqrt + norm partial --------
// grid = 32*16 = 512 blocks, 384 threads = (c in 48, mg in 8).
__global__ __launch_bounds__(384, 3) void b_kernel(const float* __restrict__ f6,
                                                   const float* __restrict__ attn,
                                                   float* __restrict__ emb,
                                                   float* __restrict__ norm_acc) {
    __shared__ float fsh[2][PCB * CTB];   // 2 x 12288 B
    __shared__ float ash[2][PCB * Mn];    // 2 x 8192 B
    __shared__ float red[6];
    const int tid = threadIdx.x;
    const int b  = blockIdx.x >> 4;
    const int ct = blockIdx.x & 15;
    const int c0 = ct * CTB;
    const int mg = tid / 48;              // 0..7 -> m quad mg*4
    const int c  = tid - mg * 48;         // 0..47

    const float* f6b = f6 + (size_t)b * HWn * Cn + c0;
    const float* atb = attn + (size_t)b * HWn * Mn;

    float4 fr0, fr1, ar0, ar1;

#define BLOAD(t) do {                                                           \
    int pbase = (t) * PCB;                                                      \
    int r0 = tid / 12, c40 = tid - r0 * 12;                                     \
    int gr0 = pbase + r0; if (gr0 > HWn - 1) gr0 = HWn - 1;                     \
    fr0 = *reinterpret_cast<const float4*>(f6b + (size_t)gr0 * Cn + c40 * 4);   \
    int f1 = tid + 384;                                                         \
    int r1 = f1 / 12, c41 = f1 - r1 * 12;                                       \
    int gr1 = pbase + r1; if (gr1 > HWn - 1) gr1 = HWn - 1;                     \
    fr1 = *reinterpret_cast<const float4*>(f6b + (size_t)gr1 * Cn + c41 * 4);   \
    int ra0 = tid >> 3, m40 = tid & 7;                                          \
    int gra0 = pbase + ra0;                                                     \
    ar0 = (gra0 < HWn) ? *reinterpret_cast<const float4*>(atb + (size_t)gra0 * Mn + m40 * 4) \
                       : make_float4(0.f, 0.f, 0.f, 0.f);                       \
    if (tid < 128) {                                                            \
        int g1 = 384 + tid; int ra1 = g1 >> 3, m41 = g1 & 7;                    \
        int gra1 = pbase + ra1;                                                 \
        ar1 = (gra1 < HWn) ? *reinterpret_cast<const float4*>(atb + (size_t)gra1 * Mn + m41 * 4) \
                           : make_float4(0.f, 0.f, 0.f, 0.f);                   \
    }                                                                           \
} while (0)

#define BWRITE(bw) do {                                                         \
    int r0 = tid / 12, c40 = tid - r0 * 12;                                     \
    *reinterpret_cast<float4*>(&fsh[bw][r0 * CTB + c40 * 4]) = fr0;             \
    int f1 = tid + 384;                                                         \
    int r1 = f1 / 12, c41 = f1 - r1 * 12;                                       \
    *reinterpret_cast<float4*>(&fsh[bw][r1 * CTB + c41 * 4]) = fr1;             \
    int ra0 = tid >> 3, m40 = tid & 7;                                          \
    *reinterpret_cast<float4*>(&ash[bw][ra0 * Mn + m40 * 4]) = ar0;             \
    if (tid < 128) {                                                            \
        int g1 = 384 + tid; int ra1 = g1 >> 3, m41 = g1 & 7;                    \
        *reinterpret_cast<float4*>(&ash[bw][ra1 * Mn + m41 * 4]) = ar1;         \
    }                                                                           \
} while (0)

    float a0 = 0.f, a1 = 0.f, a2 = 0.f, a3 = 0.f;
    BLOAD(0);
    BWRITE(0);
    int buf = 0;
    for (int t = 0; t < NPB; ++t) {
        __syncthreads();
        if (t + 1 < NPB) BLOAD(t + 1);
        const float* xp = &fsh[buf][c];
        const float* ap = &ash[buf][mg * 4];
        #pragma unroll
        for (int p = 0; p < PCB; ++p) {
            float x = xp[p * CTB];
            float4 av = *reinterpret_cast<const float4*>(ap + p * Mn);
            a0 += av.x * x; a1 += av.y * x; a2 += av.z * x; a3 += av.w * x;
        }
        if (t + 1 < NPB) BWRITE(buf ^ 1);
        buf ^= 1;
    }
#undef BLOAD
#undef BWRITE

    // fused: /HW, signed sqrt, store, norm partial
    const float inv = 1.0f / (float)HWn;
    float v0 = a0 * inv, v1 = a1 * inv, v2 = a2 * inv, v3 = a3 * inv;
    float o0 = copysignf(sqrtf(fabsf(v0) + 1e-12f), v0);
    float o1 = copysignf(sqrtf(fabsf(v1) + 1e-12f), v1);
    float o2 = copysignf(sqrtf(fabsf(v2) + 1e-12f), v2);
    float o3 = copysignf(sqrtf(fabsf(v3) + 1e-12f), v3);
    float* eb = emb + (size_t)b * KT + (size_t)(mg * 4) * Cn + c0 + c;
    eb[0]      = o0;
    eb[Cn]     = o1;
    eb[2 * Cn] = o2;
    eb[3 * Cn] = o3;
    float lsq = o0 * o0 + o1 * o1 + o2 * o2 + o3 * o3;
    #pragma unroll
    for (int off = 32; off > 0; off >>= 1) lsq += __shfl_down(lsq, off, 64);
    if ((tid & 63) == 0) red[tid >> 6] = lsq;
    __syncthreads();
    if (tid == 0)
        atomicAdd(norm_acc + b, red[0] + red[1] + red[2] + red[3] + red[4] + red[5]);
}

// ---------------- l: normalize emb (write output) + classifier ---------------
__global__ __launch_bounds__(256) void l_kernel(float* __restrict__ emb,
                                                const float* __restrict__ wC,
                                                const float* __restrict__ norm_acc,
                                                float* __restrict__ logits) {
    __shared__ float eS[Bn * 96];
    __shared__ float sS[Bn];
    const int tid = threadIdx.x;
    if (tid < Bn) sS[tid] = rsqrtf(fmaxf(norm_acc[tid], 1e-12f));
    __syncthreads();
    const int k0 = blockIdx.x * 96;
    for (int i = tid; i < Bn * 96; i += 256) {
        int b = i / 96;
        int k = i - b * 96;
        float v = emb[(size_t)b * KT + k0 + k] * sS[b];
        emb[(size_t)b * KT + k0 + k] = v;    // normalized embeddings output
        eS[i] = v * 100.0f;                   // features for logits
    }
    __syncthreads();
    if (tid < NC) {
        float acc[Bn];
        #pragma unroll
        for (int b = 0; b < Bn; ++b) acc[b] = 0.f;
        for (int kk = 0; kk < 96; ++kk) {
            float w = wC[(size_t)(k0 + kk) * NC + tid];   // coalesced
            #pragma unroll
            for (int b = 0; b < Bn; ++b) acc[b] += eS[b * 96 + kk] * w;
        }
        #pragma unroll
        for (int b = 0; b < Bn; ++b) atomicAdd(&logits[b * NC + tid], acc[b]);
    }
}

extern "C" void kernel_launch(void* const* d_in, const int* in_sizes, int n_in,
                              void* d_out, int out_size, void* d_ws, size_t ws_size,
                              hipStream_t stream) {
    const float* f6 = (const float*)d_in[0];
    const float* f7 = (const float*)d_in[1];
    const float* wA = (const float*)d_in[2];
    const float* wC = (const float*)d_in[3];
    float* out = (float*)d_out;
    float* logits = out + LOGITS_OFF;
    float* attn = out + ATTN_OFF;
    float* emb = out + EMB_OFF;
    float* norm_acc = (float*)d_ws;   // 32 floats

    z_kernel<<<32, 256, 0, stream>>>(out, norm_acc);
    a_kernel<<<Bn * NTA, 384, 0, stream>>>(f7, wA, attn);
    b_kernel<<<Bn * 16, 384, 0, stream>>>(f6, attn, emb, norm_acc);
    l_kernel<<<KT / 96, 256, 0, stream>>>(emb, wC, norm_acc, logits);
}

// Round 6
// 164.860 us; speedup vs baseline: 7.4200x; 7.4200x over previous
//
#include <hip/hip_runtime.h>
#include <hip/hip_bf16.h>

#define Bn   32
#define HWn  676
#define Cn   768
#define Mn   32
#define NC   200
#define KT   (Mn*Cn)      // 24576

#define LOGITS_OFF 0
#define ATTN_OFF   (Bn*NC)                 // 6400
#define EMB_OFF    (ATTN_OFF + Bn*HWn*Mn)  // 698624

// ws layout (floats)
#define PA_OFF   32                         // 2 x 692224
#define PB_OFF   (PA_OFF + 2*Bn*HWn*Mn)     // 2 x 786432
#define FT_OFF   (PB_OFF + 2*Bn*KT)         // 786432
#define LP_OFF   (FT_OFF + Bn*KT)           // 64*6400
#define NP_OFF   (LP_OFF + 64*6400)         // 256 norm partials

__device__ __forceinline__ void fma4(float4& a, const float4 w, const float x) {
    a.x += w.x * x; a.y += w.y * x; a.z += w.z * x; a.w += w.w * x;
}
__device__ __forceinline__ float ssq(float s) {
    return copysignf(sqrtf(fabsf(s) + 1e-12f), s);
}

// ---- a: attn GEMM. tile 128p x 32m, k-split x2. x in LDS [k][p], w via L1. ----
// grid = 32b x 6pt x 2h = 384, 128 threads.
__global__ __launch_bounds__(128, 4) void a_kernel(const float* __restrict__ f7,
                                                   const float* __restrict__ wA,
                                                   float* __restrict__ pA) {
    __shared__ float xs[2][32][132];
    const int t  = threadIdx.x;
    const int b  = blockIdx.x / 12;
    const int r2 = blockIdx.x % 12;
    const int pt = r2 >> 1;
    const int h  = r2 & 1;
    const int p0 = pt * 128;
    const int kbase = h * 384;

    const float* f7b = f7 + (size_t)b * HWn * Cn;
    const int c4  = t & 7;    // k-quad in chunk
    const int rp0 = t >> 3;   // row-pair base 0..15
    float4 v0[4], v1[4];

    const int pi = t >> 2;    // 0..31
    const int mi = t & 3;     // m0 = mi*8
    const int m0 = mi * 8;
    float4 accA[4], accB[4];
    #pragma unroll
    for (int j = 0; j < 4; ++j) {
        accA[j] = make_float4(0.f, 0.f, 0.f, 0.f);
        accB[j] = make_float4(0.f, 0.f, 0.f, 0.f);
    }

#define ALOAD(kc) do {                                                          \
    int k0_ = kbase + (kc) * 32 + c4 * 4;                                       \
    _Pragma("unroll")                                                           \
    for (int i = 0; i < 4; ++i) {                                               \
        int rp = rp0 + i * 16;                                                  \
        int g0 = p0 + 2 * rp;     if (g0 > HWn - 1) g0 = HWn - 1;               \
        int g1 = p0 + 2 * rp + 1; if (g1 > HWn - 1) g1 = HWn - 1;               \
        v0[i] = *reinterpret_cast<const float4*>(f7b + (size_t)g0 * Cn + k0_);  \
        v1[i] = *reinterpret_cast<const float4*>(f7b + (size_t)g1 * Cn + k0_);  \
    }                                                                           \
} while (0)

#define AWRITE(bw) do {                                                         \
    _Pragma("unroll")                                                           \
    for (int i = 0; i < 4; ++i) {                                               \
        int rp = rp0 + i * 16;                                                  \
        const float* a0_ = reinterpret_cast<const float*>(&v0[i]);              \
        const float* a1_ = reinterpret_cast<const float*>(&v1[i]);              \
        _Pragma("unroll")                                                       \
        for (int j = 0; j < 4; ++j) {                                           \
            float2 w2 = make_float2(a0_[j], a1_[j]);                            \
            *reinterpret_cast<float2*>(&xs[bw][c4 * 4 + j][2 * rp]) = w2;       \
        }                                                                       \
    }                                                                           \
} while (0)

    ALOAD(0);
    AWRITE(0);
    int buf = 0;
    for (int kc = 0; kc < 12; ++kc) {
        __syncthreads();
        if (kc + 1 < 12) ALOAD(kc + 1);
        const int kg0 = kbase + kc * 32;
        #pragma unroll 4
        for (int k = 0; k < 32; ++k) {
            float4 x4 = *reinterpret_cast<const float4*>(&xs[buf][k][pi * 4]);
            const float* wk = wA + (size_t)(kg0 + k) * Mn + m0;
            float4 w0 = *reinterpret_cast<const float4*>(wk);
            float4 w1 = *reinterpret_cast<const float4*>(wk + 4);
            const float* xf = reinterpret_cast<const float*>(&x4);
            fma4(accA[0], w0, xf[0]); fma4(accB[0], w1, xf[0]);
            fma4(accA[1], w0, xf[1]); fma4(accB[1], w1, xf[1]);
            fma4(accA[2], w0, xf[2]); fma4(accB[2], w1, xf[2]);
            fma4(accA[3], w0, xf[3]); fma4(accB[3], w1, xf[3]);
        }
        if (kc + 1 < 12) AWRITE(buf ^ 1);
        buf ^= 1;
    }
#undef ALOAD
#undef AWRITE

    float* dst = pA + (size_t)(h * Bn + b) * HWn * Mn;
    #pragma unroll
    for (int jp = 0; jp < 4; ++jp) {
        int p = p0 + pi * 4 + jp;
        if (p < HWn) {
            *reinterpret_cast<float4*>(dst + (size_t)p * Mn + m0)     = accA[jp];
            *reinterpret_cast<float4*>(dst + (size_t)p * Mn + m0 + 4) = accB[jp];
        }
    }
}

// ---- s: attn = pA[0] + pA[1] -> output. grid 676 x 256, 1 float4/thread. ----
__global__ __launch_bounds__(256) void s_kernel(const float* __restrict__ pA,
                                                float* __restrict__ attn) {
    int i = blockIdx.x * 256 + threadIdx.x;   // float4 index < 173056
    const float4* q0 = reinterpret_cast<const float4*>(pA);
    const float4* q1 = reinterpret_cast<const float4*>(pA + (size_t)Bn * HWn * Mn);
    float4 u = q0[i], v = q1[i];
    u.x += v.x; u.y += v.y; u.z += v.z; u.w += v.w;
    reinterpret_cast<float4*>(attn)[i] = u;
}

// ---- b: pooling GEMM. tile 128c x 32m, p-split x2. f6 in LDS [p][c], attn via L1.
// grid = 32b x 6ct x 2h = 384, 128 threads.
__global__ __launch_bounds__(128, 4) void b_kernel(const float* __restrict__ f6,
                                                   const float* __restrict__ attn,
                                                   float* __restrict__ pB) {
    __shared__ float fs[2][32][132];
    const int t  = threadIdx.x;
    const int b  = blockIdx.x / 12;
    const int r2 = blockIdx.x % 12;
    const int ct = r2 >> 1;
    const int h  = r2 & 1;
    const int c0 = ct * 128;
    const int pb0 = h * 338;

    const float* f6b = f6 + (size_t)b * HWn * Cn + c0;
    const float* atb = attn + (size_t)b * HWn * Mn;

    const int cq  = t & 31;
    const int rr0 = t >> 5;   // 0..3
    float4 u[8];

    const int ci = t >> 2;    // 0..31
    const int mi = t & 3;
    const int m0 = mi * 8;
    float4 accM0[4], accM1[4];
    #pragma unroll
    for (int j = 0; j < 4; ++j) {
        accM0[j] = make_float4(0.f, 0.f, 0.f, 0.f);
        accM1[j] = make_float4(0.f, 0.f, 0.f, 0.f);
    }

#define BLOAD(pc) do {                                                          \
    int pb_ = pb0 + (pc) * 32;                                                  \
    _Pragma("unroll")                                                           \
    for (int i = 0; i < 8; ++i) {                                               \
        int gp = pb_ + rr0 + i * 4; if (gp > HWn - 1) gp = HWn - 1;             \
        u[i] = *reinterpret_cast<const float4*>(f6b + (size_t)gp * Cn + cq * 4);\
    }                                                                           \
} while (0)

#define BWRITE(bw) do {                                                         \
    _Pragma("unroll")                                                           \
    for (int i = 0; i < 8; ++i)                                                 \
        *reinterpret_cast<float4*>(&fs[bw][rr0 + i * 4][cq * 4]) = u[i];        \
} while (0)

#define BBODY(p) do {                                                           \
    float4 x4 = *reinterpret_cast<const float4*>(&fs[buf][p][ci * 4]);          \
    const float* ar = arow + (size_t)(p) * Mn;                                  \
    float4 av0 = *reinterpret_cast<const float4*>(ar);                          \
    float4 av1 = *reinterpret_cast<const float4*>(ar + 4);                      \
    const float* xf = reinterpret_cast<const float*>(&x4);                      \
    fma4(accM0[0], av0, xf[0]); fma4(accM1[0], av1, xf[0]);                     \
    fma4(accM0[1], av0, xf[1]); fma4(accM1[1], av1, xf[1]);                     \
    fma4(accM0[2], av0, xf[2]); fma4(accM1[2], av1, xf[2]);                     \
    fma4(accM0[3], av0, xf[3]); fma4(accM1[3], av1, xf[3]);                     \
} while (0)

    BLOAD(0);
    BWRITE(0);
    int buf = 0;
    for (int pc = 0; pc < 11; ++pc) {
        __syncthreads();
        if (pc + 1 < 11) BLOAD(pc + 1);
        const float* arow = atb + (size_t)(pb0 + pc * 32) * Mn + m0;
        if (pc < 10) {
            #pragma unroll 4
            for (int p = 0; p < 32; ++p) BBODY(p);
        } else {
            #pragma unroll 2
            for (int p = 0; p < 18; ++p) BBODY(p);   // 338 = 10*32 + 18
        }
        if (pc + 1 < 11) BWRITE(buf ^ 1);
        buf ^= 1;
    }
#undef BLOAD
#undef BWRITE
#undef BBODY

    float* dst = pB + (size_t)(h * Bn + b) * KT + c0 + ci * 4;
    const float* f0 = reinterpret_cast<const float*>(&accM0[0]);
    const float* f1 = reinterpret_cast<const float*>(&accM0[1]);
    const float* f2 = reinterpret_cast<const float*>(&accM0[2]);
    const float* f3 = reinterpret_cast<const float*>(&accM0[3]);
    const float* g0 = reinterpret_cast<const float*>(&accM1[0]);
    const float* g1 = reinterpret_cast<const float*>(&accM1[1]);
    const float* g2 = reinterpret_cast<const float*>(&accM1[2]);
    const float* g3 = reinterpret_cast<const float*>(&accM1[3]);
    #pragma unroll
    for (int mj = 0; mj < 4; ++mj) {
        float4 o  = make_float4(f0[mj], f1[mj], f2[mj], f3[mj]);
        float4 o2 = make_float4(g0[mj], g1[mj], g2[mj], g3[mj]);
        *reinterpret_cast<float4*>(dst + (size_t)(m0 + mj) * Cn)     = o;
        *reinterpret_cast<float4*>(dst + (size_t)(m0 + 4 + mj) * Cn) = o2;
    }
}

// ---- rb: emb = ssqrt((pB0+pB1)/HW); also featT[k][b]; norm partials. --------
// grid = 32b x 8g = 256, 256 threads.
__global__ __launch_bounds__(256) void rb_kernel(const float* __restrict__ pB,
                                                 float* __restrict__ emb,
                                                 float* __restrict__ featT,
                                                 float* __restrict__ norm_part) {
    const int t = threadIdx.x;
    const int b = blockIdx.x >> 3;
    const int g = blockIdx.x & 7;
    const float inv = 1.0f / (float)HWn;
    const float* q0 = pB + (size_t)b * KT;
    const float* q1 = pB + (size_t)(Bn + b) * KT;
    float lsq = 0.f;
    #pragma unroll
    for (int it = 0; it < 3; ++it) {
        int e = g * 3072 + it * 1024 + t * 4;
        float4 x = *reinterpret_cast<const float4*>(q0 + e);
        float4 y = *reinterpret_cast<const float4*>(q1 + e);
        float4 o;
        o.x = ssq((x.x + y.x) * inv);
        o.y = ssq((x.y + y.y) * inv);
        o.z = ssq((x.z + y.z) * inv);
        o.w = ssq((x.w + y.w) * inv);
        *reinterpret_cast<float4*>(emb + (size_t)b * KT + e) = o;
        featT[(size_t)(e + 0) * Bn + b] = o.x;
        featT[(size_t)(e + 1) * Bn + b] = o.y;
        featT[(size_t)(e + 2) * Bn + b] = o.z;
        featT[(size_t)(e + 3) * Bn + b] = o.w;
        lsq += o.x * o.x + o.y * o.y + o.z * o.z + o.w * o.w;
    }
    #pragma unroll
    for (int o = 32; o > 0; o >>= 1) lsq += __shfl_down(lsq, o, 64);
    __shared__ float rbuf[4];
    if ((t & 63) == 0) rbuf[t >> 6] = lsq;
    __syncthreads();
    if (t == 0)
        norm_part[b * 8 + g] = rbuf[0] + rbuf[1] + rbuf[2] + rbuf[3];
}

// ---- l: partial logits. thread = (b, 4n), k-slice 384. grid 7nt x 64ks. -----
__global__ __launch_bounds__(256) void l_kernel(const float* __restrict__ featT,
                                                const float* __restrict__ wC,
                                                float* __restrict__ lp) {
    const int t  = threadIdx.x;
    const int ks = blockIdx.x & 63;
    const int nt = blockIdx.x >> 6;   // 0..6
    const int b  = t & 31;
    const int nn = t >> 5;            // 0..7
    const int n  = nt * 32 + nn * 4;
    const int k0 = ks * 384;
    if (n < NC) {
        const float* fp = featT + (size_t)k0 * Bn + b;
        const float* wp = wC + (size_t)k0 * NC + n;
        float4 acc = make_float4(0.f, 0.f, 0.f, 0.f);
        #pragma unroll 8
        for (int k = 0; k < 384; ++k) {
            float  f = fp[(size_t)k * Bn];
            float4 w = *reinterpret_cast<const float4*>(wp + (size_t)k * NC);
            acc.x += f * w.x; acc.y += f * w.y; acc.z += f * w.z; acc.w += f * w.w;
        }
        float* d = lp + (size_t)ks * 6400 + (size_t)n * Bn + b;
        d[0]      = acc.x;
        d[Bn]     = acc.y;
        d[2 * Bn] = acc.z;
        d[3 * Bn] = acc.w;
    }
}

// ---- ln: normalize emb in place. grid 768 (32b x 24), 256 thr. --------------
__global__ __launch_bounds__(256) void ln_kernel(float* __restrict__ emb,
                                                 const float* __restrict__ norm_part) {
    const int b = blockIdx.x / 24;
    const int o = (blockIdx.x % 24) * 1024 + threadIdx.x * 4;
    float ns = 0.f;
    #pragma unroll
    for (int g = 0; g < 8; ++g) ns += norm_part[b * 8 + g];
    float sc = rsqrtf(fmaxf(ns, 1e-12f));
    float4 v = *reinterpret_cast<float4*>(emb + (size_t)b * KT + o);
    v.x *= sc; v.y *= sc; v.z *= sc; v.w *= sc;
    *reinterpret_cast<float4*>(emb + (size_t)b * KT + o) = v;
}

// ---- lr: logits = sum_ks lp * scale(b) * 100. grid 25 x 256. ----------------
__global__ __launch_bounds__(256) void lr_kernel(const float* __restrict__ lp,
                                                 const float* __restrict__ norm_part,
                                                 float* __restrict__ logits) {
    const int j = blockIdx.x * 256 + threadIdx.x;   // < 6400
    const int b = j & 31;
    const int n = j >> 5;
    float s = 0.f;
    for (int ks = 0; ks < 64; ++ks) s += lp[(size_t)ks * 6400 + j];
    float ns = 0.f;
    #pragma unroll
    for (int g = 0; g < 8; ++g) ns += norm_part[b * 8 + g];
    float sc = rsqrtf(fmaxf(ns, 1e-12f)) * 100.f;
    logits[(size_t)b * NC + n] = s * sc;
}

extern "C" void kernel_launch(void* const* d_in, const int* in_sizes, int n_in,
                              void* d_out, int out_size, void* d_ws, size_t ws_size,
                              hipStream_t stream) {
    const float* f6 = (const float*)d_in[0];
    const float* f7 = (const float*)d_in[1];
    const float* wA = (const float*)d_in[2];
    const float* wC = (const float*)d_in[3];
    float* out = (float*)d_out;
    float* logits = out + LOGITS_OFF;
    float* attn = out + ATTN_OFF;
    float* emb = out + EMB_OFF;

    float* ws = (float*)d_ws;
    float* pA = ws + PA_OFF;
    float* pB = ws + PB_OFF;
    float* featT = ws + FT_OFF;
    float* lp = ws + LP_OFF;
    float* norm_part = ws + NP_OFF;

    a_kernel<<<Bn * 12, 128, 0, stream>>>(f7, wA, pA);
    s_kernel<<<676, 256, 0, stream>>>(pA, attn);
    b_kernel<<<Bn * 12, 128, 0, stream>>>(f6, attn, pB);
    rb_kernel<<<256, 256, 0, stream>>>(pB, emb, featT, norm_part);
    l_kernel<<<7 * 64, 256, 0, stream>>>(featT, wC, lp);
    ln_kernel<<<768, 256, 0, stream>>>(emb, norm_part);
    lr_kernel<<<25, 256, 0, stream>>>(lp, norm_part, logits);
}

// Round 7
// 159.992 us; speedup vs baseline: 7.6457x; 1.0304x over previous
//
#include <hip/hip_runtime.h>
#include <hip/hip_bf16.h>

#define Bn   32
#define HWn  676
#define Cn   768
#define Mn   32
#define NC   200
#define KT   (Mn*Cn)      // 24576

#define LOGITS_OFF 0
#define ATTN_OFF   (Bn*NC)                 // 6400
#define EMB_OFF    (ATTN_OFF + Bn*HWn*Mn)  // 698624

// ws layout (float offsets)
#define PA_OFF   0                          // 2 x 692224
#define PB_OFF   (PA_OFF + 2*Bn*HWn*Mn)     // 8 x 786432
#define FT_OFF   (PB_OFF + 8*Bn*KT)
#define LP_OFF   (FT_OFF + Bn*KT)           // 64 x 6400
#define NP_OFF   (LP_OFF + 64*6400)         // 256

__device__ __forceinline__ void fma4(float4& a, const float4 w, const float x) {
    a.x += w.x * x; a.y += w.y * x; a.z += w.z * x; a.w += w.w * x;
}
__device__ __forceinline__ float ssq(float s) {
    return copysignf(sqrtf(fabsf(s) + 1e-12f), s);
}

// ---- a: attn GEMM. thread = (1 p, 4 m). grid 32b x 22pt x 2h = 1408, 256 thr.
// x-tile (32p x 64k) in LDS; w from L1 (wave-shared 128B rows). acc = 1 float4.
__global__ __launch_bounds__(256, 6) void a_kernel(const float* __restrict__ f7,
                                                   const float* __restrict__ wA,
                                                   float* __restrict__ pA) {
    __shared__ float xs[2][32][68];
    const int t  = threadIdx.x;
    const int b  = blockIdx.x / 44;
    const int r  = blockIdx.x % 44;
    const int pt = r >> 1;
    const int h  = r & 1;
    const int p0 = pt * 32;
    const int kb = h * 384;

    const float* f7b = f7 + (size_t)b * HWn * Cn;

    const int sp  = t >> 4;   // stage row 0..15 (and +16)
    const int skq = t & 15;   // stage k-quad
    float4 s0, s1;

    const int cp = t >> 3;          // compute p-row 0..31
    const int m0 = (t & 7) * 4;     // m quad
    float4 acc = {0.f, 0.f, 0.f, 0.f};

    {   // prologue stage chunk 0
        int kcol = kb + skq * 4;
        int g0 = p0 + sp;      if (g0 > HWn - 1) g0 = HWn - 1;
        int g1 = p0 + sp + 16; if (g1 > HWn - 1) g1 = HWn - 1;
        s0 = *reinterpret_cast<const float4*>(f7b + (size_t)g0 * Cn + kcol);
        s1 = *reinterpret_cast<const float4*>(f7b + (size_t)g1 * Cn + kcol);
        *reinterpret_cast<float4*>(&xs[0][sp][skq * 4])      = s0;
        *reinterpret_cast<float4*>(&xs[0][sp + 16][skq * 4]) = s1;
    }

    int buf = 0;
    for (int kc = 0; kc < 6; ++kc) {
        __syncthreads();
        if (kc < 5) {   // prefetch next chunk to regs
            int kcol = kb + (kc + 1) * 64 + skq * 4;
            int g0 = p0 + sp;      if (g0 > HWn - 1) g0 = HWn - 1;
            int g1 = p0 + sp + 16; if (g1 > HWn - 1) g1 = HWn - 1;
            s0 = *reinterpret_cast<const float4*>(f7b + (size_t)g0 * Cn + kcol);
            s1 = *reinterpret_cast<const float4*>(f7b + (size_t)g1 * Cn + kcol);
        }
        const float* xrow  = xs[buf][cp];
        const float* wbase = wA + (size_t)(kb + kc * 64) * Mn + m0;
        #pragma unroll 2
        for (int k4 = 0; k4 < 16; ++k4) {
            float4 x4 = *reinterpret_cast<const float4*>(xrow + k4 * 4);
            float4 w0 = *reinterpret_cast<const float4*>(wbase + (k4 * 4 + 0) * Mn);
            float4 w1 = *reinterpret_cast<const float4*>(wbase + (k4 * 4 + 1) * Mn);
            float4 w2 = *reinterpret_cast<const float4*>(wbase + (k4 * 4 + 2) * Mn);
            float4 w3 = *reinterpret_cast<const float4*>(wbase + (k4 * 4 + 3) * Mn);
            fma4(acc, w0, x4.x);
            fma4(acc, w1, x4.y);
            fma4(acc, w2, x4.z);
            fma4(acc, w3, x4.w);
        }
        if (kc < 5) {
            *reinterpret_cast<float4*>(&xs[buf ^ 1][sp][skq * 4])      = s0;
            *reinterpret_cast<float4*>(&xs[buf ^ 1][sp + 16][skq * 4]) = s1;
        }
        buf ^= 1;
    }
    int p = p0 + cp;
    if (p < HWn)
        *reinterpret_cast<float4*>(
            pA + ((size_t)(h * Bn + b) * HWn + p) * Mn + m0) = acc;
}

// ---- s: attn = pA[0] + pA[1]. grid 676 x 256, one float4/thread. ------------
__global__ __launch_bounds__(256) void s_kernel(const float* __restrict__ pA,
                                                float* __restrict__ attn) {
    int i = blockIdx.x * 256 + threadIdx.x;   // < 173056
    const float4* q0 = reinterpret_cast<const float4*>(pA);
    const float4* q1 = reinterpret_cast<const float4*>(pA + (size_t)Bn * HWn * Mn);
    float4 u = q0[i], v = q1[i];
    u.x += v.x; u.y += v.y; u.z += v.z; u.w += v.w;
    reinterpret_cast<float4*>(attn)[i] = u;
}

// ---- b: pooling GEMM. thread = (4 c, 4 m). grid 32b x 6ct x 8h = 1536, 256 thr.
// f6-tile (16p x 128c) in LDS; attn rows from L1. acc = 4 float4. -------------
__global__ __launch_bounds__(256, 6) void b_kernel(const float* __restrict__ f6,
                                                   const float* __restrict__ attn,
                                                   float* __restrict__ pB) {
    __shared__ float fs[2][16][132];
    const int t  = threadIdx.x;
    const int b  = blockIdx.x / 48;
    const int r  = blockIdx.x % 48;
    const int ct = r >> 3;
    const int h  = r & 7;
    const int c0 = ct * 128;
    const int pb0  = h * 85;
    const int pend = (pb0 + 85 < HWn) ? (pb0 + 85) : HWn;

    const float* f6b = f6 + (size_t)b * HWn * Cn + c0;
    const float* atb = attn + (size_t)b * HWn * Mn;

    const int sp  = t >> 5;   // stage row 0..7 (and +8)
    const int scq = t & 31;   // stage c-quad
    float4 s0, s1;

    const int ci = t >> 3;          // c-quad 0..31
    const int m0 = (t & 7) * 4;     // m quad
    float4 a0 = {0,0,0,0}, a1 = {0,0,0,0}, a2 = {0,0,0,0}, a3 = {0,0,0,0};

    {   // prologue stage chunk 0
        int g0 = pb0 + sp;     if (g0 > HWn - 1) g0 = HWn - 1;
        int g1 = pb0 + sp + 8; if (g1 > HWn - 1) g1 = HWn - 1;
        s0 = *reinterpret_cast<const float4*>(f6b + (size_t)g0 * Cn + scq * 4);
        s1 = *reinterpret_cast<const float4*>(f6b + (size_t)g1 * Cn + scq * 4);
        *reinterpret_cast<float4*>(&fs[0][sp][scq * 4])     = s0;
        *reinterpret_cast<float4*>(&fs[0][sp + 8][scq * 4]) = s1;
    }

    int buf = 0;
    for (int pc = 0; pc < 6; ++pc) {
        __syncthreads();
        if (pc < 5) {
            int pbn = pb0 + (pc + 1) * 16;
            int g0 = pbn + sp;     if (g0 > HWn - 1) g0 = HWn - 1;
            int g1 = pbn + sp + 8; if (g1 > HWn - 1) g1 = HWn - 1;
            s0 = *reinterpret_cast<const float4*>(f6b + (size_t)g0 * Cn + scq * 4);
            s1 = *reinterpret_cast<const float4*>(f6b + (size_t)g1 * Cn + scq * 4);
        }
        #pragma unroll 4
        for (int pp = 0; pp < 16; ++pp) {
            int P = pb0 + pc * 16 + pp;           // wave-uniform
            float4 w4;
            if (P < pend)
                w4 = *reinterpret_cast<const float4*>(atb + (size_t)P * Mn + m0);
            else
                w4 = make_float4(0.f, 0.f, 0.f, 0.f);
            float4 x4 = *reinterpret_cast<const float4*>(&fs[buf][pp][ci * 4]);
            fma4(a0, w4, x4.x);
            fma4(a1, w4, x4.y);
            fma4(a2, w4, x4.z);
            fma4(a3, w4, x4.w);
        }
        if (pc < 5) {
            *reinterpret_cast<float4*>(&fs[buf ^ 1][sp][scq * 4])     = s0;
            *reinterpret_cast<float4*>(&fs[buf ^ 1][sp + 8][scq * 4]) = s1;
        }
        buf ^= 1;
    }

    // transpose 4c x 4m reg tile -> [m][c] rows
    float* dst = pB + (size_t)(h * Bn + b) * KT + c0 + ci * 4;
    const float* r0 = reinterpret_cast<const float*>(&a0);
    const float* r1 = reinterpret_cast<const float*>(&a1);
    const float* r2 = reinterpret_cast<const float*>(&a2);
    const float* r3 = reinterpret_cast<const float*>(&a3);
    #pragma unroll
    for (int mj = 0; mj < 4; ++mj) {
        float4 o = make_float4(r0[mj], r1[mj], r2[mj], r3[mj]);
        *reinterpret_cast<float4*>(dst + (size_t)(m0 + mj) * Cn) = o;
    }
}

// ---- rb: emb = ssqrt(sum_h pB / HW); featT; norm partials. grid 256 x 256. --
__global__ __launch_bounds__(256) void rb_kernel(const float* __restrict__ pB,
                                                 float* __restrict__ emb,
                                                 float* __restrict__ featT,
                                                 float* __restrict__ norm_part) {
    const int t = threadIdx.x;
    const int b = blockIdx.x >> 3;
    const int g = blockIdx.x & 7;
    const float inv = 1.0f / (float)HWn;
    float lsq = 0.f;
    #pragma unroll
    for (int it = 0; it < 3; ++it) {
        int e = g * 3072 + it * 1024 + t * 4;
        float4 sum = make_float4(0.f, 0.f, 0.f, 0.f);
        #pragma unroll
        for (int hh = 0; hh < 8; ++hh) {
            float4 v = *reinterpret_cast<const float4*>(
                pB + (size_t)(hh * Bn + b) * KT + e);
            sum.x += v.x; sum.y += v.y; sum.z += v.z; sum.w += v.w;
        }
        float4 o;
        o.x = ssq(sum.x * inv);
        o.y = ssq(sum.y * inv);
        o.z = ssq(sum.z * inv);
        o.w = ssq(sum.w * inv);
        *reinterpret_cast<float4*>(emb + (size_t)b * KT + e) = o;
        featT[(size_t)(e + 0) * Bn + b] = o.x;
        featT[(size_t)(e + 1) * Bn + b] = o.y;
        featT[(size_t)(e + 2) * Bn + b] = o.z;
        featT[(size_t)(e + 3) * Bn + b] = o.w;
        lsq += o.x * o.x + o.y * o.y + o.z * o.z + o.w * o.w;
    }
    #pragma unroll
    for (int o = 32; o > 0; o >>= 1) lsq += __shfl_down(lsq, o, 64);
    __shared__ float rbuf[4];
    if ((t & 63) == 0) rbuf[t >> 6] = lsq;
    __syncthreads();
    if (t == 0)
        norm_part[b * 8 + g] = rbuf[0] + rbuf[1] + rbuf[2] + rbuf[3];
}

// ---- l: partial logits, thread = (b, 4n), k-slice 384. grid 7 x 64. ---------
__global__ __launch_bounds__(256) void l_kernel(const float* __restrict__ featT,
                                                const float* __restrict__ wC,
                                                float* __restrict__ lp) {
    const int t  = threadIdx.x;
    const int ks = blockIdx.x & 63;
    const int nt = blockIdx.x >> 6;   // 0..6
    const int b  = t & 31;
    const int nn = t >> 5;            // 0..7
    const int n  = nt * 32 + nn * 4;
    const int k0 = ks * 384;
    if (n < NC) {
        const float* fp = featT + (size_t)k0 * Bn + b;
        const float* wp = wC + (size_t)k0 * NC + n;
        float4 acc = make_float4(0.f, 0.f, 0.f, 0.f);
        #pragma unroll 8
        for (int k = 0; k < 384; ++k) {
            float  f = fp[(size_t)k * Bn];
            float4 w = *reinterpret_cast<const float4*>(wp + (size_t)k * NC);
            acc.x += f * w.x; acc.y += f * w.y; acc.z += f * w.z; acc.w += f * w.w;
        }
        float* d = lp + (size_t)ks * 6400 + (size_t)n * Bn + b;
        d[0]      = acc.x;
        d[Bn]     = acc.y;
        d[2 * Bn] = acc.z;
        d[3 * Bn] = acc.w;
    }
}

// ---- ln: normalize emb in place. grid 768, 256 thr. -------------------------
__global__ __launch_bounds__(256) void ln_kernel(float* __restrict__ emb,
                                                 const float* __restrict__ norm_part) {
    const int b = blockIdx.x / 24;
    const int o = (blockIdx.x % 24) * 1024 + threadIdx.x * 4;
    float ns = 0.f;
    #pragma unroll
    for (int g = 0; g < 8; ++g) ns += norm_part[b * 8 + g];
    float sc = rsqrtf(fmaxf(ns, 1e-12f));
    float4 v = *reinterpret_cast<float4*>(emb + (size_t)b * KT + o);
    v.x *= sc; v.y *= sc; v.z *= sc; v.w *= sc;
    *reinterpret_cast<float4*>(emb + (size_t)b * KT + o) = v;
}

// ---- lr: logits = sum_ks lp * rsqrt(norm) * 100. grid 25 x 256. -------------
__global__ __launch_bounds__(256) void lr_kernel(const float* __restrict__ lp,
                                                 const float* __restrict__ norm_part,
                                                 float* __restrict__ logits) {
    const int j = blockIdx.x * 256 + threadIdx.x;   // < 6400
    const int b = j & 31;
    const int n = j >> 5;
    float s = 0.f;
    for (int ks = 0; ks < 64; ++ks) s += lp[(size_t)ks * 6400 + j];
    float ns = 0.f;
    #pragma unroll
    for (int g = 0; g < 8; ++g) ns += norm_part[b * 8 + g];
    float sc = rsqrtf(fmaxf(ns, 1e-12f)) * 100.f;
    logits[(size_t)b * NC + n] = s * sc;
}

extern "C" void kernel_launch(void* const* d_in, const int* in_sizes, int n_in,
                              void* d_out, int out_size, void* d_ws, size_t ws_size,
                              hipStream_t stream) {
    const float* f6 = (const float*)d_in[0];
    const float* f7 = (const float*)d_in[1];
    const float* wA = (const float*)d_in[2];
    const float* wC = (const float*)d_in[3];
    float* out = (float*)d_out;
    float* logits = out + LOGITS_OFF;
    float* attn = out + ATTN_OFF;
    float* emb = out + EMB_OFF;

    float* ws = (float*)d_ws;
    float* pA = ws + PA_OFF;
    float* pB = ws + PB_OFF;
    float* featT = ws + FT_OFF;
    float* lp = ws + LP_OFF;
    float* norm_part = ws + NP_OFF;

    a_kernel<<<Bn * 44, 256, 0, stream>>>(f7, wA, pA);
    s_kernel<<<676, 256, 0, stream>>>(pA, attn);
    b_kernel<<<Bn * 48, 256, 0, stream>>>(f6, attn, pB);
    rb_kernel<<<256, 256, 0, stream>>>(pB, emb, featT, norm_part);
    l_kernel<<<7 * 64, 256, 0, stream>>>(featT, wC, lp);
    ln_kernel<<<768, 256, 0, stream>>>(emb, norm_part);
    lr_kernel<<<25, 256, 0, stream>>>(lp, norm_part, logits);
}